// Round 5
// baseline (136.351 us; speedup 1.0000x reference)
//
#include <hip/hip_runtime.h>
#include <stdint.h>

#define NGRAPH 512
#define NN 64
#define INCH 256
#define TOPK 20
#define EPR 655360

// ---- workspace layout (u32 indices) ----
#define XLR_U32 0           // [512 g][128 drow][32 u32]  bf16-pairs, d-major (8 MB)
#define SL_F32  2097152     // [32768] f32
#define SR_F32  2129920     // [32768] f32
#define WPK_U32 2162688     // [16384] u32 bf16-packed Wl||Wr (64 KB)

typedef __attribute__((ext_vector_type(8))) short bf16x8;
typedef __attribute__((ext_vector_type(4))) float f32x4;
typedef __attribute__((ext_vector_type(2))) float f32x2;

static __device__ __forceinline__ uint32_t f2bfbits(float f) {
  uint32_t u = __float_as_uint(f);
  return (u + 0x7FFFu + ((u >> 16) & 1u)) >> 16;     // RNE
}
static __device__ __forceinline__ uint32_t pk2(float a, float b) {
  return f2bfbits(a) | (f2bfbits(b) << 16);
}
static __device__ __forceinline__ float lo16f(uint32_t p) { return __uint_as_float(p << 16); }
static __device__ __forceinline__ float hi16f(uint32_t p) { return __uint_as_float(p & 0xFFFF0000u); }

// ============ wpack: Wl||Wr f32 -> bf16 pairs, once per launch ============
__global__ __launch_bounds__(256) void wpack(const float* __restrict__ Wl,
                                             const float* __restrict__ Wr,
                                             uint32_t* __restrict__ wsU) {
  const int t = blockIdx.x * 256 + threadIdx.x;      // 0..16383
  const float* src = (t < 8192) ? Wl : Wr;
  const int p = t & 8191;
  float2 v = *(const float2*)(src + (size_t)p * 2);
  wsU[WPK_U32 + t] = pk2(v.x, v.y);
}

// ============ k1: per-node GEMM -> xl/xr (bf16 d-major) + Sl/Sr ============
__global__ __launch_bounds__(256) void k1(const float* __restrict__ x,
                                          uint32_t* __restrict__ wsU,
                                          const float* __restrict__ blv,
                                          const float* __restrict__ brv,
                                          const float* __restrict__ att) {
  __shared__ __align__(16) float lds[128 * 68];      // [drow][i-local], 34816 B
  float* wsF = (float*)wsU;

  const int b    = blockIdx.x;
  const int t    = threadIdx.x;
  const int w    = t >> 6;
  const int lane = t & 63;
  const int quad = lane >> 4;
  const int lo   = lane & 15;

  // --- GEMM: wave w rows r0..r0+15; ct 0..3 -> Wl cols, 4..7 -> Wr ---
  f32x4 acc[8];
  #pragma unroll
  for (int ct = 0; ct < 8; ++ct) acc[ct] = (f32x4){0.f, 0.f, 0.f, 0.f};
  const int r0 = w * 16;
  const uint4* wpk = (const uint4*)(wsU + WPK_U32);

  #pragma unroll
  for (int ks = 0; ks < 8; ++ks) {
    const int k0 = ks * 32 + quad * 8;
    const float* ap = x + (size_t)(b * NN + r0 + lo) * INCH + k0;
    float4 a0 = *(const float4*)ap;
    float4 a1 = *(const float4*)(ap + 4);
    uint4 au = { pk2(a0.x, a0.y), pk2(a0.z, a0.w), pk2(a1.x, a1.y), pk2(a1.z, a1.w) };
    bf16x8 afrag = __builtin_bit_cast(bf16x8, au);
    #pragma unroll
    for (int ct = 0; ct < 8; ++ct) {
      const int nfull = (ct & 3) * 16 + lo + ((ct >= 4) ? 64 : 0);
      uint4 bu = wpk[nfull * 32 + ks * 4 + quad];
      bf16x8 bfrag = __builtin_bit_cast(bf16x8, bu);
      acc[ct] = __builtin_amdgcn_mfma_f32_16x16x32_bf16(afrag, bfrag, acc[ct], 0, 0, 0);
    }
  }

  // --- epilogue: +bias, transpose to LDS fp32 [drow][i] ---
  #pragma unroll
  for (int ct = 0; ct < 8; ++ct) {
    const int d = (ct & 3) * 16 + lo;
    const int drow = d + ((ct < 4) ? 0 : 64);
    const float bias = ((ct < 4) ? blv : brv)[d];
    float* dst = &lds[drow * 68 + r0 + quad * 4];
    *(f32x2*)(dst)     = (f32x2){ acc[ct][0] + bias, acc[ct][1] + bias };
    *(f32x2*)(dst + 2) = (f32x2){ acc[ct][2] + bias, acc[ct][3] + bias };
  }
  __syncthreads();

  // --- Sl/Sr from fp32 LDS (threads 0..127) ---
  if (t < 128) {
    const int i = t & 63;
    const int dbase = (t < 64) ? 0 : 64;
    float s = 0.f;
    #pragma unroll 8
    for (int d = 0; d < 64; ++d)
      s = fmaf(att[d], lds[(dbase + d) * 68 + i], s);
    wsF[((t < 64) ? SL_F32 : SR_F32) + b * NN + i] = s;
  }

  // --- coalesced bf16 write-out: thread -> (drow = t>>1, half = t&1) ---
  {
    const int drow = t >> 1;
    const int off  = (t & 1) * 32;
    const float* src = &lds[drow * 68 + off];
    uint4 o[4];
    #pragma unroll
    for (int q = 0; q < 4; ++q) {
      float4 f0 = *(const float4*)(src + q * 8);
      float4 f1 = *(const float4*)(src + q * 8 + 4);
      o[q] = (uint4){ pk2(f0.x, f0.y), pk2(f0.z, f0.w), pk2(f1.x, f1.y), pk2(f1.z, f1.w) };
    }
    uint4* dst = (uint4*)(wsU + XLR_U32 + b * 4096 + drow * 32 + (t & 1) * 16);
    #pragma unroll
    for (int q = 0; q < 4; ++q) dst[q] = o[q];
  }
}

// ============ k2: attention per (graph, row-half) — grid 1024 ============
// LDS dword map
#define XLT   0      // f32 [64 d][36]  xl-half (32 i + pad)   -> 2304 dw
#define XRT   2304   // f32 [64 d][68]  xr (64 i + pad)        -> +4352 = 6656
#define ALF   6656   // f32 [32 i][68]  alpha                  -> +2176 = 8832
#define LISTS 0      // u32 [32 row][68] sorted-8 lists (aliases XLT, 2176<=2304)
#define MROW  8832   // f32 [8 seg][32 row]
#define SROW  9088   // f32 [8 seg][32 row]
#define SLL   9344   // f32 [32]
#define SRL   9376   // f32 [64]
#define ATTL  9440   // f32 [64]
#define SMEM_DW 9504

__global__ __launch_bounds__(256) void k2(const uint32_t* __restrict__ wsU,
                                          const float* __restrict__ att,
                                          float* __restrict__ out) {
  __shared__ __align__(16) uint32_t smemU[SMEM_DW];
  float* smemF = (float*)smemU;
  const float* wsF = (const float*)wsU;

  const int bx = blockIdx.x;
  const int g  = bx >> 1;
  const int h  = bx & 1;                              // row-half
  const int t  = threadIdx.x;
  const int nodeBase = g * NN;

  // ---- stage: xl-half + xr from ws (bf16 pairs) -> fp32 LDS, d-major ----
  {
    const int c = t & 15;
    #pragma unroll
    for (int k = 0; k < 4; ++k) {
      const int d = (t >> 4) + 16 * k;
      uint32_t u = wsU[XLR_U32 + g * 4096 + d * 32 + h * 16 + c];
      *(f32x2*)&smemF[XLT + d * 36 + 2 * c] = (f32x2){ lo16f(u), hi16f(u) };
    }
    const int c2 = t & 31;
    #pragma unroll
    for (int k = 0; k < 8; ++k) {
      const int d = (t >> 5) + 8 * k;
      uint32_t u = wsU[XLR_U32 + g * 4096 + (64 + d) * 32 + c2];
      *(f32x2*)&smemF[XRT + d * 68 + 2 * c2] = (f32x2){ lo16f(u), hi16f(u) };
    }
    if (t < 32)        smemF[SLL + t]       = wsF[SL_F32 + g * NN + h * 32 + t];
    else if (t < 96)   smemF[SRL + t - 32]  = wsF[SR_F32 + g * NN + (t - 32)];
    else if (t < 160)  smemF[ATTL + t - 96] = att[t - 96];
  }
  __syncthreads();

  // ---- P2: alpha = 0.6(Sl+Sr) + 0.4*sum_d a_d|xl+xr|  (128 threads, 4x4) ----
  if (t < 128) {
    const int i0 = (t >> 4) * 4;                      // 0..28
    const int j0 = (t & 15) * 4;                      // 0..60
    float pacc[4][4];
    #pragma unroll
    for (int a = 0; a < 4; ++a)
      #pragma unroll
      for (int c = 0; c < 4; ++c) pacc[a][c] = 0.f;

    #pragma unroll 4
    for (int d = 0; d < 64; ++d) {
      f32x4 xlv = *(const f32x4*)&smemF[XLT + d * 36 + i0];
      f32x4 xrv = *(const f32x4*)&smemF[XRT + d * 68 + j0];
      const float ad = smemF[ATTL + d];
      #pragma unroll
      for (int a = 0; a < 4; ++a) {
        #pragma unroll
        for (int c = 0; c < 4; ++c) {
          float s = xlv[a] + xrv[c];
          pacc[a][c] = fmaf(ad, fabsf(s), pacc[a][c]);
        }
      }
    }
    f32x4 srv = *(const f32x4*)&smemF[SRL + j0];
    #pragma unroll
    for (int a = 0; a < 4; ++a) {
      const float sl = smemF[SLL + i0 + a];
      f32x4 v;
      #pragma unroll
      for (int c = 0; c < 4; ++c)
        v[c] = 0.6f * (sl + srv[c]) + 0.4f * pacc[a][c];
      *(f32x4*)&smemF[ALF + (i0 + a) * 68 + j0] = v;
    }
  }
  __syncthreads();

  // ---- P3a: 8 threads per row scan 8 cols each; sorted-8 + (max, sumexp) ----
  {
    const int row = t & 31;
    const int seg = t >> 5;
    const int cb  = seg * 8;
    f32x4 f0 = *(const f32x4*)&smemF[ALF + row * 68 + cb];
    f32x4 f1 = *(const f32x4*)&smemF[ALF + row * 68 + cb + 4];
    float fr[8] = { f0[0], f0[1], f0[2], f0[3], f1[0], f1[1], f1[2], f1[3] };

    float mp = fr[0];
    #pragma unroll
    for (int e = 1; e < 8; ++e) mp = fmaxf(mp, fr[e]);
    float sp = 0.f;
    #pragma unroll
    for (int e = 0; e < 8; ++e) sp += __expf(fr[e] - mp);

    const int diag = h * 32 + row;
    uint32_t tk[8];
    #pragma unroll
    for (int k = 0; k < 8; ++k) tk[k] = 0u;
    #pragma unroll
    for (int e = 0; e < 8; ++e) {
      const int j = cb + e;
      uint32_t u = __float_as_uint(fr[e]);
      uint32_t key = u ^ ((uint32_t)((int32_t)u >> 31) | 0x80000000u); // order-preserving
      key = (key & 0xFFFFFFC0u) | (uint32_t)(63 - j);                  // asc-index tie-break
      key = (j == diag) ? 0u : key;
      #pragma unroll
      for (int k = 7; k >= 1; --k)
        tk[k] = (key > tk[k]) ? ((key < tk[k - 1]) ? key : tk[k - 1]) : tk[k];
      tk[0] = (key > tk[0]) ? key : tk[0];
    }
    #pragma unroll
    for (int k = 0; k < 8; ++k)
      smemU[LISTS + row * 68 + cb + k] = tk[k];
    smemF[MROW + seg * 32 + row] = mp;
    smemF[SROW + seg * 32 + row] = sp;
  }
  __syncthreads();

  // ---- P3b: 8-way merge-pop top-20 + softmax + store (32 threads) ----
  if (t < 32) {
    const int row = t;
    const int lb = LISTS + row * 68;
    float m = smemF[MROW + row];
    #pragma unroll
    for (int p = 1; p < 8; ++p) m = fmaxf(m, smemF[MROW + p * 32 + row]);
    float S = 0.f;
    #pragma unroll
    for (int p = 0; p < 8; ++p)
      S += smemF[SROW + p * 32 + row] * __expf(smemF[MROW + p * 32 + row] - m);
    const float invS = 1.0f / S;

    uint32_t h0 = smemU[lb + 0],  h1 = smemU[lb + 8],  h2 = smemU[lb + 16], h3 = smemU[lb + 24];
    uint32_t h4 = smemU[lb + 32], h5 = smemU[lb + 40], h6 = smemU[lb + 48], h7 = smemU[lb + 56];
    int p0 = 0, p1 = 0, p2 = 0, p3 = 0, p4 = 0, p5 = 0, p6 = 0, p7 = 0;
    float va[TOPK], vj[TOPK];

    #pragma unroll
    for (int k = 0; k < TOPK; ++k) {
      uint32_t m01 = (h0 > h1) ? h0 : h1;
      uint32_t m23 = (h2 > h3) ? h2 : h3;
      uint32_t m45 = (h4 > h5) ? h4 : h5;
      uint32_t m67 = (h6 > h7) ? h6 : h7;
      uint32_t ma = (m01 > m23) ? m01 : m23;
      uint32_t mb = (m45 > m67) ? m45 : m67;
      uint32_t key = (ma > mb) ? ma : mb;
      const int wsel = (key == h0) ? 0 : (key == h1) ? 1 : (key == h2) ? 2 :
                       (key == h3) ? 3 : (key == h4) ? 4 : (key == h5) ? 5 :
                       (key == h6) ? 6 : 7;

      int np = ((wsel == 0) ? p0 : (wsel == 1) ? p1 : (wsel == 2) ? p2 : (wsel == 3) ? p3 :
                (wsel == 4) ? p4 : (wsel == 5) ? p5 : (wsel == 6) ? p6 : p7) + 1;
      uint32_t hn = (np < 8) ? smemU[lb + wsel * 8 + np] : 0u;   // issue load early

      uint32_t ub = (key & 0x80000000u) ? (key ^ 0x80000000u) : ~key;
      float alpha = __uint_as_float(ub & 0xFFFFFFC0u);
      const int j = 63 - (int)(key & 63u);
      va[k] = __expf(alpha - m) * invS;
      vj[k] = (float)(nodeBase + j);

      p0 += (wsel == 0); p1 += (wsel == 1); p2 += (wsel == 2); p3 += (wsel == 3);
      p4 += (wsel == 4); p5 += (wsel == 5); p6 += (wsel == 6); p7 += (wsel == 7);
      h0 = (wsel == 0) ? hn : h0;  h1 = (wsel == 1) ? hn : h1;
      h2 = (wsel == 2) ? hn : h2;  h3 = (wsel == 3) ? hn : h3;
      h4 = (wsel == 4) ? hn : h4;  h5 = (wsel == 5) ? hn : h5;
      h6 = (wsel == 6) ? hn : h6;  h7 = (wsel == 7) ? hn : h7;
    }

    const int gout = bx * 32 + row;                    // = g*64 + h*32 + row
    const float vi = (float)gout;
    float4* o0 = (float4*)(out + (size_t)gout * 20);
    float4* o1 = (float4*)(out + EPR + (size_t)gout * 20);
    float4* o2 = (float4*)(out + 2 * (size_t)EPR + (size_t)gout * 20);
    const float4 vi4 = { vi, vi, vi, vi };
    #pragma unroll
    for (int kk = 0; kk < 5; ++kk) {
      o0[kk] = vi4;
      o1[kk] = (float4){ vj[4 * kk], vj[4 * kk + 1], vj[4 * kk + 2], vj[4 * kk + 3] };
      o2[kk] = (float4){ va[4 * kk], va[4 * kk + 1], va[4 * kk + 2], va[4 * kk + 3] };
    }
  }
}

extern "C" void kernel_launch(void* const* d_in, const int* in_sizes, int n_in,
                              void* d_out, int out_size, void* d_ws, size_t ws_size,
                              hipStream_t stream) {
  const float* x   = (const float*)d_in[0];
  // d_in[1] = edge_index, d_in[2] = batch: fully-connected structure is implicit
  const float* Wl  = (const float*)d_in[3];
  const float* bl  = (const float*)d_in[4];
  const float* Wr  = (const float*)d_in[5];
  const float* br  = (const float*)d_in[6];
  const float* att = (const float*)d_in[7];
  uint32_t* wsU = (uint32_t*)d_ws;                     // needs ~8.4 MB

  wpack<<<dim3(64),   dim3(256), 0, stream>>>(Wl, Wr, wsU);
  k1   <<<dim3(NGRAPH), dim3(256), 0, stream>>>(x, wsU, bl, br, att);
  k2   <<<dim3(2 * NGRAPH), dim3(256), 0, stream>>>(wsU, att, (float*)d_out);
}